// Round 1
// baseline (340.835 us; speedup 1.0000x reference)
//
#include <hip/hip_runtime.h>
#include <hip/hip_bf16.h>
#include <stdint.h>

// Sparse block conv 3x3, NHWC, H=W=1024, C=COUT=64, 32x32 blocks, 512 active.
// Strategy: bf16 MFMA (32x32x16) on gathered blocks, zero-fill inactive blocks.

typedef __bf16 bf16x8 __attribute__((ext_vector_type(8)));
typedef float f32x16 __attribute__((ext_vector_type(16)));

#define WFRAG_BYTES 73728  // 9 taps * 4 ksteps * 2 ntiles * 64 lanes * 16B

__device__ __forceinline__ unsigned f2bf1(float f) {
    unsigned u = __float_as_uint(f);
    u += 0x7fffu + ((u >> 16) & 1u);   // round-to-nearest-even
    return u >> 16;
}
__device__ __forceinline__ unsigned pack2(float lo, float hi) {
    return f2bf1(lo) | (f2bf1(hi) << 16);
}

// Repack Wk [3][3][64][64] f32 -> per-lane MFMA B fragments, bf16.
// Fragment (tap, s, nt): lane l holds W[ky][kx][s*16 + 8*(l>>5) + e][nt*32 + (l&31)], e=0..7.
__global__ void k_repack(const float* __restrict__ Wk, unsigned short* __restrict__ wfrag) {
    int t = blockIdx.x * 256 + threadIdx.x;
    if (t >= 9 * 4 * 2 * 64) return;
    int lane = t & 63;
    int nt   = (t >> 6) & 1;
    int s    = (t >> 7) & 3;
    int tap  = t >> 9;
    int co = nt * 32 + (lane & 31);
    int cb = s * 16 + 8 * (lane >> 5);
    const float* wp = Wk + (tap * 64 + cb) * 64 + co;   // stride over c is 64 floats
    uint4 v;
    v.x = pack2(wp[0],   wp[64]);
    v.y = pack2(wp[128], wp[192]);
    v.z = pack2(wp[256], wp[320]);
    v.w = pack2(wp[384], wp[448]);
    ((uint4*)wfrag)[t] = v;
}

__global__ void k_flags0(int* __restrict__ flags) {
    flags[blockIdx.x * 256 + threadIdx.x] = 0;
}
__global__ void k_scatter(const int* __restrict__ ids, int* __restrict__ flags) {
    int t = blockIdx.x * 256 + threadIdx.x;
    if (t < 512) flags[ids[t]] = 1;
}

// One workgroup per 32x32 spatial block. 4 waves.
// Active: 4 passes of 8 output rows; LDS patch 10 rows x 34 x 64ch bf16 (swizzled).
// Wave w owns output rows {2w, 2w+1} of the pass, all 64 couts (2 N-tiles of 32).
__global__ __launch_bounds__(256) void k_conv(
    const float* __restrict__ x, const float* __restrict__ bias,
    const uint4* __restrict__ wfrag, const int* __restrict__ flags,
    float* __restrict__ out)
{
    __shared__ __align__(16) char lds[10 * 34 * 128];
    const int bid = blockIdx.x;
    const int bi = bid >> 5, bj = bid & 31;
    const int tid = threadIdx.x;

    if (flags[bid] == 0) {
        // zero-fill this 32x32x64 output block
        const float4 z = make_float4(0.f, 0.f, 0.f, 0.f);
        for (int py = 0; py < 32; ++py) {
            float4* rowp = (float4*)(out + ((bi * 32 + py) * 1024 + bj * 32) * 64);
            rowp[tid]       = z;
            rowp[tid + 256] = z;
        }
        return;
    }

    const int lane = tid & 63;
    const int wv = tid >> 6;
    const float b0 = bias[lane & 31];
    const float b1 = bias[32 + (lane & 31)];

    for (int p = 0; p < 4; ++p) {
        __syncthreads();   // protect LDS from previous pass's readers
        // ---- stage: 10x34 pixels, 64 ch, f32 -> bf16, XOR-swizzled LDS ----
        for (int t = tid; t < 10 * 34 * 8; t += 256) {
            int cg  = t & 7;        // 8-channel group
            int pix = t >> 3;       // 0..339
            int ly  = pix / 34;
            int lx  = pix - ly * 34;
            int yg = bi * 32 + p * 8 - 1 + ly;
            int xg = bj * 32 - 1 + lx;
            uint4 v = make_uint4(0u, 0u, 0u, 0u);
            if ((unsigned)yg < 1024u && (unsigned)xg < 1024u) {
                const float4* gp = (const float4*)(x + ((yg * 1024 + xg) * 64 + cg * 8));
                float4 v0 = gp[0], v1 = gp[1];
                v.x = pack2(v0.x, v0.y);
                v.y = pack2(v0.z, v0.w);
                v.z = pack2(v1.x, v1.y);
                v.w = pack2(v1.z, v1.w);
            }
            int byteoff = (pix * 128 + cg * 16) ^ ((lx & 7) << 4);
            *(uint4*)(lds + byteoff) = v;
        }
        __syncthreads();

        // ---- compute: acc[dm][nt], dm = row within wave pair, nt = cout tile ----
        f32x16 acc[2][2];
        #pragma unroll
        for (int dm = 0; dm < 2; ++dm)
            #pragma unroll
            for (int r = 0; r < 16; ++r) { acc[dm][0][r] = b0; acc[dm][1][r] = b1; }

        const int xl = lane & 31;            // A row = output pixel x
        const int chalf = 16 * (lane >> 5);  // byte offset of lane's channel half

        #pragma unroll
        for (int ky = 0; ky < 3; ++ky) {
            #pragma unroll
            for (int kx = 0; kx < 3; ++kx) {
                #pragma unroll
                for (int s = 0; s < 4; ++s) {
                    int fi = ((ky * 3 + kx) * 8 + s * 2) * 64 + lane;
                    bf16x8 bf0 = *(const bf16x8*)(wfrag + fi);
                    bf16x8 bf1 = *(const bf16x8*)(wfrag + fi + 64);
                    #pragma unroll
                    for (int dm = 0; dm < 2; ++dm) {
                        int yl = 2 * wv + dm + ky;       // patch row
                        int xp = xl + kx;                // patch col
                        int byteoff = ((yl * 34 + xp) * 128 + s * 32 + chalf) ^ ((xp & 7) << 4);
                        bf16x8 a = *(const bf16x8*)(lds + byteoff);
                        acc[dm][0] = __builtin_amdgcn_mfma_f32_32x32x16_bf16(a, bf0, acc[dm][0], 0, 0, 0);
                        acc[dm][1] = __builtin_amdgcn_mfma_f32_32x32x16_bf16(a, bf1, acc[dm][1], 0, 0, 0);
                    }
                }
            }
        }

        // ---- epilogue: C/D layout col=lane&31, row=(r&3)+8*(r>>2)+4*(lane>>5) ----
        #pragma unroll
        for (int dm = 0; dm < 2; ++dm) {
            int row = bi * 32 + p * 8 + 2 * wv + dm;
            float* orow = out + (row * 1024 + bj * 32) * 64;
            #pragma unroll
            for (int nt = 0; nt < 2; ++nt) {
                int co = nt * 32 + (lane & 31);
                #pragma unroll
                for (int r = 0; r < 16; ++r) {
                    int px = (r & 3) + 8 * (r >> 2) + 4 * (lane >> 5);
                    orow[px * 64 + co] = acc[dm][nt][r];
                }
            }
        }
    }
}

extern "C" void kernel_launch(void* const* d_in, const int* in_sizes, int n_in,
                              void* d_out, int out_size, void* d_ws, size_t ws_size,
                              hipStream_t stream) {
    const float* x    = (const float*)d_in[0];
    const int*   ids  = (const int*)d_in[1];
    const float* Wk   = (const float*)d_in[2];
    const float* bias = (const float*)d_in[3];
    float* out = (float*)d_out;

    unsigned short* wfrag = (unsigned short*)d_ws;
    int* flags = (int*)((char*)d_ws + WFRAG_BYTES);

    k_repack<<<18, 256, 0, stream>>>(Wk, wfrag);
    k_flags0<<<4, 256, 0, stream>>>(flags);
    k_scatter<<<2, 256, 0, stream>>>(ids, flags);
    k_conv<<<1024, 256, 0, stream>>>(x, bias, (const uint4*)wfrag, flags, out);
}

// Round 2
// 121.918 us; speedup vs baseline: 2.7956x; 2.7956x over previous
//
#include <hip/hip_runtime.h>
#include <hip/hip_bf16.h>
#include <stdint.h>

// Sparse block conv 3x3, NHWC, H=W=1024, C=COUT=64, 32x32 blocks, 512 active.
// bf16 MFMA (32x32x16). One workgroup per 8-row strip (4 strips per block).

typedef __bf16 bf16x8 __attribute__((ext_vector_type(8)));
typedef float f32x16 __attribute__((ext_vector_type(16)));

#define WFRAG_BYTES 73728  // 9 taps * 4 ksteps * 2 ntiles * 64 lanes * 16B

__device__ __forceinline__ unsigned f2bf1(float f) {
    unsigned u = __float_as_uint(f);
    u += 0x7fffu + ((u >> 16) & 1u);   // round-to-nearest-even
    return u >> 16;
}
__device__ __forceinline__ unsigned pack2(float lo, float hi) {
    return f2bf1(lo) | (f2bf1(hi) << 16);
}

// Repack Wk [3][3][64][64] f32 -> per-lane MFMA B fragments, bf16.
// Fragment (tap, s, nt): lane l holds W[ky][kx][s*16 + 8*(l>>5) + e][nt*32 + (l&31)], e=0..7.
__global__ void k_repack(const float* __restrict__ Wk, unsigned short* __restrict__ wfrag) {
    int t = blockIdx.x * 256 + threadIdx.x;
    if (t >= 9 * 4 * 2 * 64) return;
    int lane = t & 63;
    int nt   = (t >> 6) & 1;
    int s    = (t >> 7) & 3;
    int tap  = t >> 9;
    int co = nt * 32 + (lane & 31);
    int cb = s * 16 + 8 * (lane >> 5);
    const float* wp = Wk + (tap * 64 + cb) * 64 + co;
    uint4 v;
    v.x = pack2(wp[0],   wp[64]);
    v.y = pack2(wp[128], wp[192]);
    v.z = pack2(wp[256], wp[320]);
    v.w = pack2(wp[384], wp[448]);
    ((uint4*)wfrag)[t] = v;
}

__global__ void k_flags0(int* __restrict__ flags) {
    flags[blockIdx.x * 256 + threadIdx.x] = 0;
}
__global__ void k_scatter(const int* __restrict__ ids, int* __restrict__ flags) {
    int t = blockIdx.x * 256 + threadIdx.x;
    if (t < 512) flags[ids[t]] = 1;
}

// One workgroup per 8-row strip: strip = bid*4 + p. 4 waves, 256 threads.
// Active: stage 10x34x64 patch (f32 -> bf16, XOR-swizzled LDS), then each
// wave computes 2 output rows x 64 couts via 32x32x16 bf16 MFMA.
__global__ __launch_bounds__(256, 3) void k_conv(
    const float* __restrict__ x, const float* __restrict__ bias,
    const uint4* __restrict__ wfrag, const int* __restrict__ flags,
    float* __restrict__ out)
{
    __shared__ __align__(16) char lds[10 * 34 * 128];
    const int strip = blockIdx.x;
    const int bid = strip >> 2, p = strip & 3;
    const int bi = bid >> 5, bj = bid & 31;
    const int tid = threadIdx.x;

    if (flags[bid] == 0) {
        // zero-fill 8 output rows of this block
        const float4 z = make_float4(0.f, 0.f, 0.f, 0.f);
        for (int py = 0; py < 8; ++py) {
            float4* rowp = (float4*)(out + ((bi * 32 + p * 8 + py) * 1024 + bj * 32) * 64);
            rowp[tid]       = z;
            rowp[tid + 256] = z;
        }
        return;
    }

    const int lane = tid & 63;
    const int wv = tid >> 6;

    // ---- stage: 10x34 pixels, 64 ch, f32 -> bf16, XOR-swizzled LDS ----
    for (int t = tid; t < 10 * 34 * 8; t += 256) {
        int cg  = t & 7;        // 8-channel group
        int pix = t >> 3;       // 0..339
        int ly  = pix / 34;
        int lx  = pix - ly * 34;
        int yg = bi * 32 + p * 8 - 1 + ly;
        int xg = bj * 32 - 1 + lx;
        bf16x8 v = {};
        if ((unsigned)yg < 1024u && (unsigned)xg < 1024u) {
            const float4* gp = (const float4*)(x + ((yg * 1024 + xg) * 64 + cg * 8));
            float4 v0 = gp[0], v1 = gp[1];
            v[0] = (__bf16)v0.x; v[1] = (__bf16)v0.y;
            v[2] = (__bf16)v0.z; v[3] = (__bf16)v0.w;
            v[4] = (__bf16)v1.x; v[5] = (__bf16)v1.y;
            v[6] = (__bf16)v1.z; v[7] = (__bf16)v1.w;
        }
        int byteoff = (pix * 128 + cg * 16) ^ ((lx & 7) << 4);
        *(bf16x8*)(lds + byteoff) = v;
    }
    __syncthreads();

    // ---- compute: acc[dm][nt], dm = row within wave pair, nt = cout tile ----
    const float b0 = bias[lane & 31];
    const float b1 = bias[32 + (lane & 31)];
    f32x16 acc[2][2];
    #pragma unroll
    for (int dm = 0; dm < 2; ++dm)
        #pragma unroll
        for (int r = 0; r < 16; ++r) { acc[dm][0][r] = b0; acc[dm][1][r] = b1; }

    const int xl = lane & 31;            // A row = output pixel x
    const int chalf = 16 * (lane >> 5);  // byte offset of lane's channel half

    #pragma unroll
    for (int ky = 0; ky < 3; ++ky) {
        #pragma unroll
        for (int kx = 0; kx < 3; ++kx) {
            #pragma unroll
            for (int s = 0; s < 4; ++s) {
                int fi = ((ky * 3 + kx) * 8 + s * 2) * 64 + lane;
                bf16x8 bf0 = *(const bf16x8*)(wfrag + fi);
                bf16x8 bf1 = *(const bf16x8*)(wfrag + fi + 64);
                #pragma unroll
                for (int dm = 0; dm < 2; ++dm) {
                    int yl = 2 * wv + dm + ky;       // patch row
                    int xp = xl + kx;                // patch col
                    int byteoff = ((yl * 34 + xp) * 128 + s * 32 + chalf) ^ ((xp & 7) << 4);
                    bf16x8 a = *(const bf16x8*)(lds + byteoff);
                    acc[dm][0] = __builtin_amdgcn_mfma_f32_32x32x16_bf16(a, bf0, acc[dm][0], 0, 0, 0);
                    acc[dm][1] = __builtin_amdgcn_mfma_f32_32x32x16_bf16(a, bf1, acc[dm][1], 0, 0, 0);
                }
            }
        }
    }

    // ---- epilogue: C/D layout col=lane&31, row=(r&3)+8*(r>>2)+4*(lane>>5) ----
    #pragma unroll
    for (int dm = 0; dm < 2; ++dm) {
        int row = bi * 32 + p * 8 + 2 * wv + dm;
        float* orow = out + (row * 1024 + bj * 32) * 64;
        #pragma unroll
        for (int nt = 0; nt < 2; ++nt) {
            int co = nt * 32 + (lane & 31);
            #pragma unroll
            for (int r = 0; r < 16; ++r) {
                int px = (r & 3) + 8 * (r >> 2) + 4 * (lane >> 5);
                orow[px * 64 + co] = acc[dm][nt][r];
            }
        }
    }
}

extern "C" void kernel_launch(void* const* d_in, const int* in_sizes, int n_in,
                              void* d_out, int out_size, void* d_ws, size_t ws_size,
                              hipStream_t stream) {
    const float* x    = (const float*)d_in[0];
    const int*   ids  = (const int*)d_in[1];
    const float* Wk   = (const float*)d_in[2];
    const float* bias = (const float*)d_in[3];
    float* out = (float*)d_out;

    unsigned short* wfrag = (unsigned short*)d_ws;
    int* flags = (int*)((char*)d_ws + WFRAG_BYTES);

    k_repack<<<18, 256, 0, stream>>>(Wk, wfrag);
    k_flags0<<<4, 256, 0, stream>>>(flags);
    k_scatter<<<2, 256, 0, stream>>>(ids, flags);
    k_conv<<<4096, 256, 0, stream>>>(x, bias, (const uint4*)wfrag, flags, out);
}

// Round 4
// 84.231 us; speedup vs baseline: 4.0464x; 1.4474x over previous
//
#include <hip/hip_runtime.h>
#include <hip/hip_bf16.h>
#include <stdint.h>

// Sparse block conv 3x3, NHWC, H=W=1024, C=COUT=64, 32x32 blocks, 512 active.
// bf16 MFMA 32x32x16. One 512-thread workgroup per 8-row strip; 8 waves,
// each wave computes 1 output row x 64 couts. XCD-chunk swizzle for L2 halo
// reuse; nontemporal output stores.

typedef __bf16 bf16x8 __attribute__((ext_vector_type(8)));
typedef float f32x16 __attribute__((ext_vector_type(16)));
typedef float f32x4 __attribute__((ext_vector_type(4)));

#define WFRAG_BYTES 73728  // 9 taps * 4 ksteps * 2 ntiles * 64 lanes * 16B

__device__ __forceinline__ unsigned f2bf1(float f) {
    unsigned u = __float_as_uint(f);
    u += 0x7fffu + ((u >> 16) & 1u);
    return u >> 16;
}
__device__ __forceinline__ unsigned pack2(float lo, float hi) {
    return f2bf1(lo) | (f2bf1(hi) << 16);
}

// blocks 0..17: repack Wk [3][3][64][64] f32 -> per-lane MFMA B fragments (bf16).
// block 18: zero flags (1024) then scatter 512 active ids.
__global__ __launch_bounds__(256) void k_prep(const float* __restrict__ Wk,
                                              const int* __restrict__ ids,
                                              unsigned short* __restrict__ wfrag,
                                              int* __restrict__ flags) {
    int tid = threadIdx.x;
    if (blockIdx.x == 18) {
        #pragma unroll
        for (int i = 0; i < 4; ++i) flags[tid * 4 + i] = 0;
        __syncthreads();
        flags[ids[tid]] = 1;
        flags[ids[tid + 256]] = 1;
        return;
    }
    int t = blockIdx.x * 256 + tid;   // < 4608 = 9*4*2*64
    int lane = t & 63;
    int nt   = (t >> 6) & 1;
    int s    = (t >> 7) & 3;
    int tap  = t >> 9;
    int co = nt * 32 + (lane & 31);
    int cb = s * 16 + 8 * (lane >> 5);
    const float* wp = Wk + (tap * 64 + cb) * 64 + co;
    uint4 v;
    v.x = pack2(wp[0],   wp[64]);
    v.y = pack2(wp[128], wp[192]);
    v.z = pack2(wp[256], wp[320]);
    v.w = pack2(wp[384], wp[448]);
    ((uint4*)wfrag)[t] = v;
}

// strip' = (w&7)*512 + (w>>3): XCD k owns a contiguous 1/8 of the image rows,
// and the 4 strips of each block run temporally close on the same XCD.
__global__ __launch_bounds__(512, 4) void k_conv(
    const float* __restrict__ x, const float* __restrict__ bias,
    const uint4* __restrict__ wfrag, const int* __restrict__ flags,
    float* __restrict__ out)
{
    __shared__ __align__(16) char lds[10 * 34 * 128];
    const int w = blockIdx.x;
    const int strip = ((w & 7) << 9) | (w >> 3);
    const int bid = strip >> 2, p = strip & 3;
    const int bi = bid >> 5, bj = bid & 31;
    const int tid = threadIdx.x;

    if (flags[bid] == 0) {
        // 8 rows; one row = 32px*64ch = 512 f32x4 -> one store per thread per row
        const f32x4 z = {0.f, 0.f, 0.f, 0.f};
        for (int py = 0; py < 8; ++py) {
            f32x4* rowp = (f32x4*)(out + ((bi * 32 + p * 8 + py) * 1024 + bj * 32) * 64);
            __builtin_nontemporal_store(z, rowp + tid);
        }
        return;
    }

    const int lane = tid & 63;
    const int wv = tid >> 6;   // 0..7 = output row within strip

    // ---- stage: 10x34 pixels, 64ch f32 -> bf16, XOR-swizzled LDS.
    // unit u: pixel u>>2, 16-channel quarter u&3 (64B global read, 32B LDS write)
    for (int u = tid; u < 1360; u += 512) {
        int q   = u & 3;
        int pix = u >> 2;       // 0..339
        int ly  = pix / 34;
        int lx  = pix - ly * 34;
        int yg = bi * 32 + p * 8 - 1 + ly;
        int xg = bj * 32 - 1 + lx;
        bf16x8 v0 = {}, v1 = {};
        if ((unsigned)yg < 1024u && (unsigned)xg < 1024u) {
            const float4* gp = (const float4*)(x + ((yg * 1024 + xg) * 64 + q * 16));
            float4 a = gp[0], b = gp[1], c = gp[2], d = gp[3];
            v0[0] = (__bf16)a.x; v0[1] = (__bf16)a.y; v0[2] = (__bf16)a.z; v0[3] = (__bf16)a.w;
            v0[4] = (__bf16)b.x; v0[5] = (__bf16)b.y; v0[6] = (__bf16)b.z; v0[7] = (__bf16)b.w;
            v1[0] = (__bf16)c.x; v1[1] = (__bf16)c.y; v1[2] = (__bf16)c.z; v1[3] = (__bf16)c.w;
            v1[4] = (__bf16)d.x; v1[5] = (__bf16)d.y; v1[6] = (__bf16)d.z; v1[7] = (__bf16)d.w;
        }
        int base = pix * 128 + q * 32;
        int swz  = (lx & 7) << 4;
        *(bf16x8*)(lds + (base ^ swz))        = v0;
        *(bf16x8*)(lds + ((base + 16) ^ swz)) = v1;
    }
    __syncthreads();

    // ---- compute: wave wv -> output row p*8+wv, patch rows wv..wv+2 ----
    const float b0 = bias[lane & 31];
    const float b1 = bias[32 + (lane & 31)];
    f32x16 acc0, acc1;
    #pragma unroll
    for (int r = 0; r < 16; ++r) { acc0[r] = b0; acc1[r] = b1; }

    const int xl = lane & 31;
    const int chalf = 16 * (lane >> 5);

    #pragma unroll
    for (int kx = 0; kx < 3; ++kx) {
        int xp = xl + kx;
        int swz = (xp & 7) << 4;
        #pragma unroll
        for (int s = 0; s < 4; ++s) {
            int cbyte = s * 32 + chalf;
            bf16x8 a0 = *(const bf16x8*)(lds + ((((wv + 0) * 34 + xp) * 128 + cbyte) ^ swz));
            bf16x8 a1 = *(const bf16x8*)(lds + ((((wv + 1) * 34 + xp) * 128 + cbyte) ^ swz));
            bf16x8 a2 = *(const bf16x8*)(lds + ((((wv + 2) * 34 + xp) * 128 + cbyte) ^ swz));
            #pragma unroll
            for (int ky = 0; ky < 3; ++ky) {
                int fi = ((ky * 3 + kx) * 8 + s * 2) * 64 + lane;
                bf16x8 bf0 = *(const bf16x8*)(wfrag + fi);
                bf16x8 bf1 = *(const bf16x8*)(wfrag + fi + 64);
                bf16x8 a = (ky == 0) ? a0 : (ky == 1) ? a1 : a2;
                acc0 = __builtin_amdgcn_mfma_f32_32x32x16_bf16(a, bf0, acc0, 0, 0, 0);
                acc1 = __builtin_amdgcn_mfma_f32_32x32x16_bf16(a, bf1, acc1, 0, 0, 0);
            }
        }
    }

    // ---- epilogue: C/D layout col=lane&31, row=(r&3)+8*(r>>2)+4*(lane>>5) ----
    const int row = bi * 32 + p * 8 + wv;
    float* orow = out + (row * 1024 + bj * 32) * 64;
    const int co = lane & 31;
    #pragma unroll
    for (int r = 0; r < 16; ++r) {
        int px = (r & 3) + 8 * (r >> 2) + 4 * (lane >> 5);
        __builtin_nontemporal_store(acc0[r], orow + px * 64 + co);
        __builtin_nontemporal_store(acc1[r], orow + px * 64 + co + 32);
    }
}

extern "C" void kernel_launch(void* const* d_in, const int* in_sizes, int n_in,
                              void* d_out, int out_size, void* d_ws, size_t ws_size,
                              hipStream_t stream) {
    const float* x    = (const float*)d_in[0];
    const int*   ids  = (const int*)d_in[1];
    const float* Wk   = (const float*)d_in[2];
    const float* bias = (const float*)d_in[3];
    float* out = (float*)d_out;

    unsigned short* wfrag = (unsigned short*)d_ws;
    int* flags = (int*)((char*)d_ws + WFRAG_BYTES);

    k_prep<<<19, 256, 0, stream>>>(Wk, ids, wfrag, flags);
    k_conv<<<4096, 512, 0, stream>>>(x, bias, (const uint4*)wfrag, flags, out);
}

// Round 5
// 83.902 us; speedup vs baseline: 4.0623x; 1.0039x over previous
//
#include <hip/hip_runtime.h>
#include <hip/hip_bf16.h>
#include <stdint.h>

// Sparse block conv 3x3, NHWC, H=W=1024, C=COUT=64, 32x32 blocks, 512 active.
// bf16 MFMA 32x32x16. One 512-thread workgroup per 8-row strip; 8 waves,
// each computes 1 output row x 64 couts. XCD-chunk swizzle; nontemporal
// stores; T14 async-stage split (issue all global loads, then convert+write).

typedef __bf16 bf16x8 __attribute__((ext_vector_type(8)));
typedef float f32x16 __attribute__((ext_vector_type(16)));
typedef float f32x4 __attribute__((ext_vector_type(4)));

#define WFRAG_BYTES 73728  // 9 taps * 4 ksteps * 2 ntiles * 64 lanes * 16B

__device__ __forceinline__ unsigned f2bf1(float f) {
    unsigned u = __float_as_uint(f);
    u += 0x7fffu + ((u >> 16) & 1u);
    return u >> 16;
}
__device__ __forceinline__ unsigned pack2(float lo, float hi) {
    return f2bf1(lo) | (f2bf1(hi) << 16);
}

// blocks 0..17: repack Wk [3][3][64][64] f32 -> per-lane MFMA B fragments (bf16).
// block 18: zero flags (1024) then scatter 512 active ids.
__global__ __launch_bounds__(256) void k_prep(const float* __restrict__ Wk,
                                              const int* __restrict__ ids,
                                              unsigned short* __restrict__ wfrag,
                                              int* __restrict__ flags) {
    int tid = threadIdx.x;
    if (blockIdx.x == 18) {
        #pragma unroll
        for (int i = 0; i < 4; ++i) flags[tid * 4 + i] = 0;
        __syncthreads();
        flags[ids[tid]] = 1;
        flags[ids[tid + 256]] = 1;
        return;
    }
    int t = blockIdx.x * 256 + tid;   // < 4608 = 9*4*2*64
    int lane = t & 63;
    int nt   = (t >> 6) & 1;
    int s    = (t >> 7) & 3;
    int tap  = t >> 9;
    int co = nt * 32 + (lane & 31);
    int cb = s * 16 + 8 * (lane >> 5);
    const float* wp = Wk + (tap * 64 + cb) * 64 + co;
    uint4 v;
    v.x = pack2(wp[0],   wp[64]);
    v.y = pack2(wp[128], wp[192]);
    v.z = pack2(wp[256], wp[320]);
    v.w = pack2(wp[384], wp[448]);
    ((uint4*)wfrag)[t] = v;
}

// strip' = (w&7)*512 + (w>>3): XCD k owns a contiguous 1/8 of the image rows,
// and the 4 strips of each block run temporally close on the same XCD.
__global__ __launch_bounds__(512, 4) void k_conv(
    const float* __restrict__ x, const float* __restrict__ bias,
    const uint4* __restrict__ wfrag, const int* __restrict__ flags,
    float* __restrict__ out)
{
    __shared__ __align__(16) char lds[10 * 34 * 128];
    const int w = blockIdx.x;
    const int strip = ((w & 7) << 9) | (w >> 3);
    const int bid = strip >> 2, p = strip & 3;
    const int bi = bid >> 5, bj = bid & 31;
    const int tid = threadIdx.x;

    if (flags[bid] == 0) {
        const f32x4 z = {0.f, 0.f, 0.f, 0.f};
        for (int py = 0; py < 8; ++py) {
            f32x4* rowp = (f32x4*)(out + ((bi * 32 + p * 8 + py) * 1024 + bj * 32) * 64);
            __builtin_nontemporal_store(z, rowp + tid);
        }
        return;
    }

    const int lane = tid & 63;
    const int wv = tid >> 6;   // 0..7 = output row within strip

    // ---- stage (T14 split): phase A issues all global loads, phase B
    // converts f32->bf16 and writes XOR-swizzled LDS.
    // unit u: pixel u>>2 (0..339), 16-channel quarter u&3. 1360 units total:
    // k=0,1 all threads; k=2 only tid<336.
    float4 ra[3][4];
    int rbase[3];
    int rswz[3];
    #pragma unroll
    for (int k = 0; k < 3; ++k) {
        int u = tid + k * 512;
        bool live = (k < 2) || (tid < 336);
        int q   = u & 3;
        int pix = u >> 2;
        int ly  = pix / 34;
        int lx  = pix - ly * 34;
        int yg = bi * 32 + p * 8 - 1 + ly;
        int xg = bj * 32 - 1 + lx;
        rbase[k] = pix * 128 + q * 32;
        rswz[k]  = (lx & 7) << 4;
        ra[k][0] = make_float4(0.f, 0.f, 0.f, 0.f);
        ra[k][1] = make_float4(0.f, 0.f, 0.f, 0.f);
        ra[k][2] = make_float4(0.f, 0.f, 0.f, 0.f);
        ra[k][3] = make_float4(0.f, 0.f, 0.f, 0.f);
        if (live && (unsigned)yg < 1024u && (unsigned)xg < 1024u) {
            const float4* gp = (const float4*)(x + ((yg * 1024 + xg) * 64 + q * 16));
            ra[k][0] = gp[0]; ra[k][1] = gp[1]; ra[k][2] = gp[2]; ra[k][3] = gp[3];
        }
        if (!live) rbase[k] = -1;
    }
    #pragma unroll
    for (int k = 0; k < 3; ++k) {
        if (rbase[k] < 0) continue;
        bf16x8 v0, v1;
        float4 a = ra[k][0], b = ra[k][1], c = ra[k][2], d = ra[k][3];
        v0[0] = (__bf16)a.x; v0[1] = (__bf16)a.y; v0[2] = (__bf16)a.z; v0[3] = (__bf16)a.w;
        v0[4] = (__bf16)b.x; v0[5] = (__bf16)b.y; v0[6] = (__bf16)b.z; v0[7] = (__bf16)b.w;
        v1[0] = (__bf16)c.x; v1[1] = (__bf16)c.y; v1[2] = (__bf16)c.z; v1[3] = (__bf16)c.w;
        v1[4] = (__bf16)d.x; v1[5] = (__bf16)d.y; v1[6] = (__bf16)d.z; v1[7] = (__bf16)d.w;
        *(bf16x8*)(lds + (rbase[k] ^ rswz[k]))          = v0;
        *(bf16x8*)(lds + ((rbase[k] + 16) ^ rswz[k]))   = v1;
    }
    __syncthreads();

    // ---- compute: wave wv -> output row p*8+wv, patch rows wv..wv+2 ----
    const float b0 = bias[lane & 31];
    const float b1 = bias[32 + (lane & 31)];
    f32x16 acc0, acc1;
    #pragma unroll
    for (int r = 0; r < 16; ++r) { acc0[r] = b0; acc1[r] = b1; }

    const int xl = lane & 31;
    const int chalf = 16 * (lane >> 5);

    #pragma unroll
    for (int kx = 0; kx < 3; ++kx) {
        int xp = xl + kx;
        int swz = (xp & 7) << 4;
        #pragma unroll
        for (int s = 0; s < 4; ++s) {
            int cbyte = s * 32 + chalf;
            bf16x8 a0 = *(const bf16x8*)(lds + ((((wv + 0) * 34 + xp) * 128 + cbyte) ^ swz));
            bf16x8 a1 = *(const bf16x8*)(lds + ((((wv + 1) * 34 + xp) * 128 + cbyte) ^ swz));
            bf16x8 a2 = *(const bf16x8*)(lds + ((((wv + 2) * 34 + xp) * 128 + cbyte) ^ swz));
            #pragma unroll
            for (int ky = 0; ky < 3; ++ky) {
                int fi = ((ky * 3 + kx) * 8 + s * 2) * 64 + lane;
                bf16x8 bf0 = *(const bf16x8*)(wfrag + fi);
                bf16x8 bf1 = *(const bf16x8*)(wfrag + fi + 64);
                bf16x8 a = (ky == 0) ? a0 : (ky == 1) ? a1 : a2;
                acc0 = __builtin_amdgcn_mfma_f32_32x32x16_bf16(a, bf0, acc0, 0, 0, 0);
                acc1 = __builtin_amdgcn_mfma_f32_32x32x16_bf16(a, bf1, acc1, 0, 0, 0);
            }
        }
    }

    // ---- epilogue: C/D layout col=lane&31, row=(r&3)+8*(r>>2)+4*(lane>>5) ----
    const int row = bi * 32 + p * 8 + wv;
    float* orow = out + (row * 1024 + bj * 32) * 64;
    const int co = lane & 31;
    #pragma unroll
    for (int r = 0; r < 16; ++r) {
        int px = (r & 3) + 8 * (r >> 2) + 4 * (lane >> 5);
        __builtin_nontemporal_store(acc0[r], orow + px * 64 + co);
        __builtin_nontemporal_store(acc1[r], orow + px * 64 + co + 32);
    }
}

extern "C" void kernel_launch(void* const* d_in, const int* in_sizes, int n_in,
                              void* d_out, int out_size, void* d_ws, size_t ws_size,
                              hipStream_t stream) {
    const float* x    = (const float*)d_in[0];
    const int*   ids  = (const int*)d_in[1];
    const float* Wk   = (const float*)d_in[2];
    const float* bias = (const float*)d_in[3];
    float* out = (float*)d_out;

    unsigned short* wfrag = (unsigned short*)d_ws;
    int* flags = (int*)((char*)d_ws + WFRAG_BYTES);

    k_prep<<<19, 256, 0, stream>>>(Wk, ids, wfrag, flags);
    k_conv<<<4096, 512, 0, stream>>>(x, bias, (const uint4*)wfrag, flags, out);
}

// Round 6
// 82.078 us; speedup vs baseline: 4.1526x; 1.0222x over previous
//
#include <hip/hip_runtime.h>
#include <hip/hip_bf16.h>
#include <stdint.h>

// Sparse block conv 3x3, NHWC, H=W=1024, C=COUT=64, 32x32 blocks, 512 active.
// bf16 MFMA 32x32x16. One 512-thread workgroup per PAIR of strips:
// zero-fill one inactive 8-row strip + conv one active 8-row strip.
// NACT=512 is exactly half of 1024 blocks -> perfect static balance.

typedef __bf16 bf16x8 __attribute__((ext_vector_type(8)));
typedef float f32x16 __attribute__((ext_vector_type(16)));
typedef float f32x4 __attribute__((ext_vector_type(4)));

#define WFRAG_BYTES 73728          // 9 taps * 4 ksteps * 2 ntiles * 64 lanes * 16B
#define FLAGS_OFF   WFRAG_BYTES    // 1024 ints
#define INACT_OFF   (FLAGS_OFF + 4096)   // 512 ints
#define CNT_OFF     (INACT_OFF + 2048)   // 1 int

__device__ __forceinline__ unsigned f2bf1(float f) {
    unsigned u = __float_as_uint(f);
    u += 0x7fffu + ((u >> 16) & 1u);
    return u >> 16;
}
__device__ __forceinline__ unsigned pack2(float lo, float hi) {
    return f2bf1(lo) | (f2bf1(hi) << 16);
}

// blocks 0..17: repack Wk [3][3][64][64] f32 -> per-lane MFMA B fragments (bf16).
// block 18: flags scatter + compact the 512 inactive block ids.
__global__ __launch_bounds__(256) void k_prep(const float* __restrict__ Wk,
                                              const int* __restrict__ ids,
                                              unsigned short* __restrict__ wfrag,
                                              int* __restrict__ flags,
                                              int* __restrict__ inact,
                                              int* __restrict__ cnt) {
    int tid = threadIdx.x;
    if (blockIdx.x == 18) {
        #pragma unroll
        for (int i = 0; i < 4; ++i) flags[tid * 4 + i] = 0;
        if (tid == 0) cnt[0] = 0;
        __syncthreads();
        flags[ids[tid]] = 1;
        flags[ids[tid + 256]] = 1;
        __syncthreads();
        #pragma unroll
        for (int i = 0; i < 4; ++i) {
            int b = tid * 4 + i;
            if (flags[b] == 0) {
                int pos = atomicAdd(cnt, 1);   // list order irrelevant: set semantics
                inact[pos] = b;
            }
        }
        return;
    }
    int t = blockIdx.x * 256 + tid;   // < 4608 = 9*4*2*64
    int lane = t & 63;
    int nt   = (t >> 6) & 1;
    int s    = (t >> 7) & 3;
    int tap  = t >> 9;
    int co = nt * 32 + (lane & 31);
    int cb = s * 16 + 8 * (lane >> 5);
    const float* wp = Wk + (tap * 64 + cb) * 64 + co;
    uint4 v;
    v.x = pack2(wp[0],   wp[64]);
    v.y = pack2(wp[128], wp[192]);
    v.z = pack2(wp[256], wp[320]);
    v.w = pack2(wp[384], wp[448]);
    ((uint4*)wfrag)[t] = v;
}

// w -> u = (w&7)*256 + w>>3: each XCD owns a contiguous 1/8 of the list,
// the 4 strips of each active block run temporally adjacent on one XCD.
__global__ __launch_bounds__(512, 4) void k_conv(
    const float* __restrict__ x, const float* __restrict__ bias,
    const uint4* __restrict__ wfrag, const int* __restrict__ ids,
    const int* __restrict__ inact, float* __restrict__ out)
{
    __shared__ __align__(16) char lds[10 * 34 * 128];
    const int w = blockIdx.x;
    const int u = ((w & 7) << 8) | (w >> 3);
    const int li = u >> 2, p = u & 3;
    const int tid = threadIdx.x;

    // ---- zero-fill one inactive strip (fire-and-forget stores) ----
    {
        const int zb = inact[li];
        const int zbi = zb >> 5, zbj = zb & 31;
        const f32x4 z = {0.f, 0.f, 0.f, 0.f};
        #pragma unroll
        for (int py = 0; py < 8; ++py) {
            f32x4* rowp = (f32x4*)(out + ((zbi * 32 + p * 8 + py) * 1024 + zbj * 32) * 64);
            __builtin_nontemporal_store(z, rowp + tid);
        }
    }

    // ---- conv one active strip ----
    const int bid = ids[li];
    const int bi = bid >> 5, bj = bid & 31;
    const int lane = tid & 63;
    const int wv = tid >> 6;   // 0..7 = output row within strip

    // stage: 10x34 pixels, 64ch f32 -> bf16, XOR-swizzled LDS.
    // unit u: pixel u>>2 (0..339), 16-channel quarter u&3; 1360 units.
    float4 ra[3][4];
    int rbase[3];
    int rswz[3];
    #pragma unroll
    for (int k = 0; k < 3; ++k) {
        int uu = tid + k * 512;
        bool live = (k < 2) || (tid < 336);
        int q   = uu & 3;
        int pix = uu >> 2;
        int ly  = pix / 34;
        int lx  = pix - ly * 34;
        int yg = bi * 32 + p * 8 - 1 + ly;
        int xg = bj * 32 - 1 + lx;
        rbase[k] = pix * 128 + q * 32;
        rswz[k]  = (lx & 7) << 4;
        ra[k][0] = make_float4(0.f, 0.f, 0.f, 0.f);
        ra[k][1] = make_float4(0.f, 0.f, 0.f, 0.f);
        ra[k][2] = make_float4(0.f, 0.f, 0.f, 0.f);
        ra[k][3] = make_float4(0.f, 0.f, 0.f, 0.f);
        if (live && (unsigned)yg < 1024u && (unsigned)xg < 1024u) {
            const float4* gp = (const float4*)(x + ((yg * 1024 + xg) * 64 + q * 16));
            ra[k][0] = gp[0]; ra[k][1] = gp[1]; ra[k][2] = gp[2]; ra[k][3] = gp[3];
        }
        if (!live) rbase[k] = -1;
    }
    #pragma unroll
    for (int k = 0; k < 3; ++k) {
        if (rbase[k] < 0) continue;
        bf16x8 v0, v1;
        float4 a = ra[k][0], b = ra[k][1], c = ra[k][2], d = ra[k][3];
        v0[0] = (__bf16)a.x; v0[1] = (__bf16)a.y; v0[2] = (__bf16)a.z; v0[3] = (__bf16)a.w;
        v0[4] = (__bf16)b.x; v0[5] = (__bf16)b.y; v0[6] = (__bf16)b.z; v0[7] = (__bf16)b.w;
        v1[0] = (__bf16)c.x; v1[1] = (__bf16)c.y; v1[2] = (__bf16)c.z; v1[3] = (__bf16)c.w;
        v1[4] = (__bf16)d.x; v1[5] = (__bf16)d.y; v1[6] = (__bf16)d.z; v1[7] = (__bf16)d.w;
        *(bf16x8*)(lds + (rbase[k] ^ rswz[k]))        = v0;
        *(bf16x8*)(lds + ((rbase[k] + 16) ^ rswz[k])) = v1;
    }
    __syncthreads();

    // compute: wave wv -> output row p*8+wv, patch rows wv..wv+2
    const float b0 = bias[lane & 31];
    const float b1 = bias[32 + (lane & 31)];
    f32x16 acc0, acc1;
    #pragma unroll
    for (int r = 0; r < 16; ++r) { acc0[r] = b0; acc1[r] = b1; }

    const int xl = lane & 31;
    const int chalf = 16 * (lane >> 5);

    #pragma unroll
    for (int kx = 0; kx < 3; ++kx) {
        int xp = xl + kx;
        int swz = (xp & 7) << 4;
        #pragma unroll
        for (int s = 0; s < 4; ++s) {
            int cbyte = s * 32 + chalf;
            bf16x8 a0 = *(const bf16x8*)(lds + ((((wv + 0) * 34 + xp) * 128 + cbyte) ^ swz));
            bf16x8 a1 = *(const bf16x8*)(lds + ((((wv + 1) * 34 + xp) * 128 + cbyte) ^ swz));
            bf16x8 a2 = *(const bf16x8*)(lds + ((((wv + 2) * 34 + xp) * 128 + cbyte) ^ swz));
            #pragma unroll
            for (int ky = 0; ky < 3; ++ky) {
                int fi = ((ky * 3 + kx) * 8 + s * 2) * 64 + lane;
                bf16x8 bf0 = *(const bf16x8*)(wfrag + fi);
                bf16x8 bf1 = *(const bf16x8*)(wfrag + fi + 64);
                bf16x8 a = (ky == 0) ? a0 : (ky == 1) ? a1 : a2;
                acc0 = __builtin_amdgcn_mfma_f32_32x32x16_bf16(a, bf0, acc0, 0, 0, 0);
                acc1 = __builtin_amdgcn_mfma_f32_32x32x16_bf16(a, bf1, acc1, 0, 0, 0);
            }
        }
    }

    // epilogue: C/D layout col=lane&31, row=(r&3)+8*(r>>2)+4*(lane>>5)
    const int row = bi * 32 + p * 8 + wv;
    float* orow = out + (row * 1024 + bj * 32) * 64;
    const int co = lane & 31;
    #pragma unroll
    for (int r = 0; r < 16; ++r) {
        int px = (r & 3) + 8 * (r >> 2) + 4 * (lane >> 5);
        __builtin_nontemporal_store(acc0[r], orow + px * 64 + co);
        __builtin_nontemporal_store(acc1[r], orow + px * 64 + co + 32);
    }
}

extern "C" void kernel_launch(void* const* d_in, const int* in_sizes, int n_in,
                              void* d_out, int out_size, void* d_ws, size_t ws_size,
                              hipStream_t stream) {
    const float* x    = (const float*)d_in[0];
    const int*   ids  = (const int*)d_in[1];
    const float* Wk   = (const float*)d_in[2];
    const float* bias = (const float*)d_in[3];
    float* out = (float*)d_out;

    unsigned short* wfrag = (unsigned short*)d_ws;
    int* flags = (int*)((char*)d_ws + FLAGS_OFF);
    int* inact = (int*)((char*)d_ws + INACT_OFF);
    int* cnt   = (int*)((char*)d_ws + CNT_OFF);

    k_prep<<<19, 256, 0, stream>>>(Wk, ids, wfrag, flags, inact, cnt);
    k_conv<<<2048, 512, 0, stream>>>(x, bias, (const uint4*)wfrag, ids, inact, out);
}

// Round 7
// 79.511 us; speedup vs baseline: 4.2866x; 1.0323x over previous
//
#include <hip/hip_runtime.h>
#include <hip/hip_bf16.h>
#include <stdint.h>

// Sparse block conv 3x3, NHWC, H=W=1024, C=COUT=64, 32x32 blocks, 512 active.
// bf16 MFMA 32x32x16. One 512-thread workgroup per PAIR of 16-row strips:
// zero-fill one inactive strip + conv one active strip. 8 waves; each wave
// computes 2 adjacent output rows x 64 couts. Stage 18x34x64 patch in LDS
// (XOR-swizzled). XCD-chunk swizzle; nontemporal stores.

typedef __bf16 bf16x8 __attribute__((ext_vector_type(8)));
typedef float f32x16 __attribute__((ext_vector_type(16)));
typedef float f32x4 __attribute__((ext_vector_type(4)));

#define WFRAG_BYTES 73728          // 9 taps * 4 ksteps * 2 ntiles * 64 lanes * 16B
#define FLAGS_OFF   WFRAG_BYTES    // 1024 ints
#define INACT_OFF   (FLAGS_OFF + 4096)   // 512 ints
#define CNT_OFF     (INACT_OFF + 2048)   // 1 int

__device__ __forceinline__ unsigned f2bf1(float f) {
    unsigned u = __float_as_uint(f);
    u += 0x7fffu + ((u >> 16) & 1u);
    return u >> 16;
}
__device__ __forceinline__ unsigned pack2(float lo, float hi) {
    return f2bf1(lo) | (f2bf1(hi) << 16);
}

// blocks 0..17: repack Wk [3][3][64][64] f32 -> per-lane MFMA B fragments (bf16).
// block 18: flags scatter + compact the 512 inactive block ids.
__global__ __launch_bounds__(256) void k_prep(const float* __restrict__ Wk,
                                              const int* __restrict__ ids,
                                              unsigned short* __restrict__ wfrag,
                                              int* __restrict__ flags,
                                              int* __restrict__ inact,
                                              int* __restrict__ cnt) {
    int tid = threadIdx.x;
    if (blockIdx.x == 18) {
        #pragma unroll
        for (int i = 0; i < 4; ++i) flags[tid * 4 + i] = 0;
        if (tid == 0) cnt[0] = 0;
        __syncthreads();
        flags[ids[tid]] = 1;
        flags[ids[tid + 256]] = 1;
        __syncthreads();
        #pragma unroll
        for (int i = 0; i < 4; ++i) {
            int b = tid * 4 + i;
            if (flags[b] == 0) {
                int pos = atomicAdd(cnt, 1);   // list order irrelevant: set semantics
                inact[pos] = b;
            }
        }
        return;
    }
    int t = blockIdx.x * 256 + tid;   // < 4608 = 9*4*2*64
    int lane = t & 63;
    int nt   = (t >> 6) & 1;
    int s    = (t >> 7) & 3;
    int tap  = t >> 9;
    int co = nt * 32 + (lane & 31);
    int cb = s * 16 + 8 * (lane >> 5);
    const float* wp = Wk + (tap * 64 + cb) * 64 + co;
    uint4 v;
    v.x = pack2(wp[0],   wp[64]);
    v.y = pack2(wp[128], wp[192]);
    v.z = pack2(wp[256], wp[320]);
    v.w = pack2(wp[384], wp[448]);
    ((uint4*)wfrag)[t] = v;
}

// w -> u = (w&7)*128 + w>>3: each XCD owns a contiguous 1/8 of the list;
// the 2 strips of each active block run temporally adjacent on one XCD.
__global__ __launch_bounds__(512, 4) void k_conv(
    const float* __restrict__ x, const float* __restrict__ bias,
    const uint4* __restrict__ wfrag, const int* __restrict__ ids,
    const int* __restrict__ inact, float* __restrict__ out)
{
    __shared__ __align__(16) char lds[18 * 34 * 128];   // 78336 B
    const int w = blockIdx.x;
    const int u = ((w & 7) << 7) | (w >> 3);
    const int li = u >> 1, p = u & 1;
    const int tid = threadIdx.x;

    // ---- zero-fill one inactive 16-row strip ----
    {
        const int zb = inact[li];
        const int zbi = zb >> 5, zbj = zb & 31;
        const f32x4 z = {0.f, 0.f, 0.f, 0.f};
        #pragma unroll
        for (int py = 0; py < 16; ++py) {
            f32x4* rowp = (f32x4*)(out + ((zbi * 32 + p * 16 + py) * 1024 + zbj * 32) * 64);
            __builtin_nontemporal_store(z, rowp + tid);
        }
    }

    // ---- conv one active 16-row strip ----
    const int bid = ids[li];
    const int bi = bid >> 5, bj = bid & 31;
    const int lane = tid & 63;
    const int wv = tid >> 6;   // 0..7; wave owns output rows {2wv, 2wv+1}

    // stage: 18x34 pixels, 64ch f32 -> bf16, XOR-swizzled LDS.
    // unit t: pixel t>>2 (0..611), 16-channel quarter t&3 (64B read, 32B write)
    for (int t = tid; t < 18 * 34 * 4; t += 512) {
        int q   = t & 3;
        int pix = t >> 2;
        int ly  = pix / 34;
        int lx  = pix - ly * 34;
        int yg = bi * 32 + p * 16 - 1 + ly;
        int xg = bj * 32 - 1 + lx;
        bf16x8 v0 = {}, v1 = {};
        if ((unsigned)yg < 1024u && (unsigned)xg < 1024u) {
            const float4* gp = (const float4*)(x + ((yg * 1024 + xg) * 64 + q * 16));
            float4 a = gp[0], b = gp[1], c = gp[2], d = gp[3];
            v0[0] = (__bf16)a.x; v0[1] = (__bf16)a.y; v0[2] = (__bf16)a.z; v0[3] = (__bf16)a.w;
            v0[4] = (__bf16)b.x; v0[5] = (__bf16)b.y; v0[6] = (__bf16)b.z; v0[7] = (__bf16)b.w;
            v1[0] = (__bf16)c.x; v1[1] = (__bf16)c.y; v1[2] = (__bf16)c.z; v1[3] = (__bf16)c.w;
            v1[4] = (__bf16)d.x; v1[5] = (__bf16)d.y; v1[6] = (__bf16)d.z; v1[7] = (__bf16)d.w;
        }
        int base = pix * 128 + q * 32;
        int swz  = (lx & 7) << 4;
        *(bf16x8*)(lds + (base ^ swz))        = v0;
        *(bf16x8*)(lds + ((base + 16) ^ swz)) = v1;
    }
    __syncthreads();

    // compute: wave wv -> output rows 2wv,2wv+1; patch rows 2wv..2wv+3
    const float b0 = bias[lane & 31];
    const float b1 = bias[32 + (lane & 31)];
    f32x16 acc[2][2];
    #pragma unroll
    for (int dm = 0; dm < 2; ++dm)
        #pragma unroll
        for (int r = 0; r < 16; ++r) { acc[dm][0][r] = b0; acc[dm][1][r] = b1; }

    const int xl = lane & 31;
    const int chalf = 16 * (lane >> 5);

    #pragma unroll
    for (int kx = 0; kx < 3; ++kx) {
        int xp = xl + kx;
        int swz = (xp & 7) << 4;
        #pragma unroll
        for (int s = 0; s < 4; ++s) {
            int cbyte = s * 32 + chalf;
            bf16x8 a0 = *(const bf16x8*)(lds + ((((2 * wv + 0) * 34 + xp) * 128 + cbyte) ^ swz));
            bf16x8 a1 = *(const bf16x8*)(lds + ((((2 * wv + 1) * 34 + xp) * 128 + cbyte) ^ swz));
            bf16x8 a2 = *(const bf16x8*)(lds + ((((2 * wv + 2) * 34 + xp) * 128 + cbyte) ^ swz));
            bf16x8 a3 = *(const bf16x8*)(lds + ((((2 * wv + 3) * 34 + xp) * 128 + cbyte) ^ swz));
            #pragma unroll
            for (int ky = 0; ky < 3; ++ky) {
                int fi = ((ky * 3 + kx) * 8 + s * 2) * 64 + lane;
                bf16x8 bf0 = *(const bf16x8*)(wfrag + fi);
                bf16x8 bf1 = *(const bf16x8*)(wfrag + fi + 64);
                bf16x8 ar0 = (ky == 0) ? a0 : (ky == 1) ? a1 : a2;   // row 2wv
                bf16x8 ar1 = (ky == 0) ? a1 : (ky == 1) ? a2 : a3;   // row 2wv+1
                acc[0][0] = __builtin_amdgcn_mfma_f32_32x32x16_bf16(ar0, bf0, acc[0][0], 0, 0, 0);
                acc[0][1] = __builtin_amdgcn_mfma_f32_32x32x16_bf16(ar0, bf1, acc[0][1], 0, 0, 0);
                acc[1][0] = __builtin_amdgcn_mfma_f32_32x32x16_bf16(ar1, bf0, acc[1][0], 0, 0, 0);
                acc[1][1] = __builtin_amdgcn_mfma_f32_32x32x16_bf16(ar1, bf1, acc[1][1], 0, 0, 0);
            }
        }
    }

    // epilogue: C/D layout col=lane&31, row=(r&3)+8*(r>>2)+4*(lane>>5)
    const int co = lane & 31;
    #pragma unroll
    for (int dm = 0; dm < 2; ++dm) {
        int row = bi * 32 + p * 16 + 2 * wv + dm;
        float* orow = out + (row * 1024 + bj * 32) * 64;
        #pragma unroll
        for (int r = 0; r < 16; ++r) {
            int px = (r & 3) + 8 * (r >> 2) + 4 * (lane >> 5);
            __builtin_nontemporal_store(acc[dm][0][r], orow + px * 64 + co);
            __builtin_nontemporal_store(acc[dm][1][r], orow + px * 64 + co + 32);
        }
    }
}

extern "C" void kernel_launch(void* const* d_in, const int* in_sizes, int n_in,
                              void* d_out, int out_size, void* d_ws, size_t ws_size,
                              hipStream_t stream) {
    const float* x    = (const float*)d_in[0];
    const int*   ids  = (const int*)d_in[1];
    const float* Wk   = (const float*)d_in[2];
    const float* bias = (const float*)d_in[3];
    float* out = (float*)d_out;

    unsigned short* wfrag = (unsigned short*)d_ws;
    int* flags = (int*)((char*)d_ws + FLAGS_OFF);
    int* inact = (int*)((char*)d_ws + INACT_OFF);
    int* cnt   = (int*)((char*)d_ws + CNT_OFF);

    k_prep<<<19, 256, 0, stream>>>(Wk, ids, wfrag, flags, inact, cnt);
    k_conv<<<1024, 512, 0, stream>>>(x, bias, (const uint4*)wfrag, ids, inact, out);
}